// Round 8
// baseline (280.879 us; speedup 1.0000x reference)
//
#include <hip/hip_runtime.h>
#include <math.h>

// ---------------------------------------------------------------------------
// ManifoldNet SPD network, fused in log-domain.
// prep_k: wave-parallel softmax of all 10 weight tensors + logm of input.
// 10 convs (zero-pad fused into staging) on the 6 unique components of the
// symmetric log field -> expm once.
// Conv v7: per-channel register batching -- all K^2 weight float4s and K
// pixel rows loaded to regs first (one latency exposure), then a pure FMA
// block. unroll 1 on cc prevents cross-iteration hoisting (v5 lesson).
// ---------------------------------------------------------------------------

#define DEVFN __device__ __forceinline__

DEVFN void jrot(float A[3][3], float V[3][3], int p, int q) {
    float apq = A[p][q];
    if (fabsf(apq) < 1e-30f) return;
    float app = A[p][p], aqq = A[q][q];
    float tau = (aqq - app) / (2.0f * apq);
    float t = copysignf(1.0f, tau) / (fabsf(tau) + sqrtf(1.0f + tau * tau));
    float c = rsqrtf(1.0f + t * t);
    float s = t * c;
    int r = 3 - p - q;
    float arp = A[r][p], arq = A[r][q];
    A[p][p] = app - t * apq;
    A[q][q] = aqq + t * apq;
    A[p][q] = 0.0f; A[q][p] = 0.0f;
    A[r][p] = c * arp - s * arq; A[p][r] = A[r][p];
    A[r][q] = s * arp + c * arq; A[q][r] = A[r][q];
#pragma unroll
    for (int i = 0; i < 3; ++i) {
        float vip = V[i][p], viq = V[i][q];
        V[i][p] = c * vip - s * viq;
        V[i][q] = s * vip + c * viq;
    }
}

DEVFN void eigh3(float A[3][3], float V[3][3]) {
    V[0][0] = 1.f; V[0][1] = 0.f; V[0][2] = 0.f;
    V[1][0] = 0.f; V[1][1] = 1.f; V[1][2] = 0.f;
    V[2][0] = 0.f; V[2][1] = 0.f; V[2][2] = 1.f;
#pragma unroll
    for (int s = 0; s < 6; ++s) {
        jrot(A, V, 0, 1);
        jrot(A, V, 0, 2);
        jrot(A, V, 1, 2);
    }
}

struct WP {
    const float* src[10];
    float* dst[10];
    int Co[10];
    int n[10];
};

// blocks 0..9: wave-parallel softmax for layer blockIdx.x.
// blocks 10..: logm of matrices. x: [n,3,3] SPD -> out planar [6][n].
__global__ __launch_bounds__(256)
void prep_k(WP wp, const float* __restrict__ x, float* __restrict__ out, int n) {
    if (blockIdx.x < 10) {
        const int l = blockIdx.x;
        const int wv = threadIdx.x >> 6;
        const int lane = threadIdx.x & 63;
        const int Co = wp.Co[l], nn = wp.n[l];
        for (int co = wv; co < Co; co += 4) {
            const float* src = wp.src[l] + (size_t)co * nn;
            float v0 = (lane < nn) ? src[lane] : -1e30f;
            float v1 = (lane + 64 < nn) ? src[lane + 64] : -1e30f;
            float v2 = (lane + 128 < nn) ? src[lane + 128] : -1e30f;
            float mx = fmaxf(fmaxf(v0, v1), v2);
#pragma unroll
            for (int off = 32; off; off >>= 1)
                mx = fmaxf(mx, __shfl_xor(mx, off));
            float e0 = (lane < nn) ? expf(v0 - mx) : 0.f;
            float e1 = (lane + 64 < nn) ? expf(v1 - mx) : 0.f;
            float e2 = (lane + 128 < nn) ? expf(v2 - mx) : 0.f;
            float s = e0 + e1 + e2;
#pragma unroll
            for (int off = 32; off; off >>= 1)
                s += __shfl_xor(s, off);
            float inv = 1.0f / s;
            float* dst = wp.dst[l] + (size_t)co * nn;
            if (lane < nn) dst[lane] = e0 * inv;
            if (lane + 64 < nn) dst[lane + 64] = e1 * inv;
            if (lane + 128 < nn) dst[lane + 128] = e2 * inv;
        }
        return;
    }
    int i = (blockIdx.x - 10) * 256 + threadIdx.x;
    if (i >= n) return;
    const float* m = x + (size_t)i * 9;
    float a01 = 0.5f * (m[1] + m[3]);
    float a02 = 0.5f * (m[2] + m[6]);
    float a12 = 0.5f * (m[5] + m[7]);
    float A[3][3] = {{m[0], a01, a02}, {a01, m[4], a12}, {a02, a12, m[8]}};
    float V[3][3];
    eigh3(A, V);
    float d0 = logf(fmaxf(A[0][0], 1e-30f));
    float d1 = logf(fmaxf(A[1][1], 1e-30f));
    float d2 = logf(fmaxf(A[2][2], 1e-30f));
    float L00 = V[0][0]*d0*V[0][0] + V[0][1]*d1*V[0][1] + V[0][2]*d2*V[0][2];
    float L01 = V[0][0]*d0*V[1][0] + V[0][1]*d1*V[1][1] + V[0][2]*d2*V[1][2];
    float L02 = V[0][0]*d0*V[2][0] + V[0][1]*d1*V[2][1] + V[0][2]*d2*V[2][2];
    float L11 = V[1][0]*d0*V[1][0] + V[1][1]*d1*V[1][1] + V[1][2]*d2*V[1][2];
    float L12 = V[1][0]*d0*V[2][0] + V[1][1]*d1*V[2][1] + V[1][2]*d2*V[2][2];
    float L22 = V[2][0]*d0*V[2][0] + V[2][1]*d1*V[2][1] + V[2][2]*d2*V[2][2];
    out[0 * (size_t)n + i] = L00;
    out[1 * (size_t)n + i] = L01;
    out[2 * (size_t)n + i] = L02;
    out[3 * (size_t)n + i] = L11;
    out[4 * (size_t)n + i] = L12;
    out[5 * (size_t)n + i] = L22;
}

__global__ void expm_k(const float* __restrict__ Lp, float* __restrict__ out, int n) {
    int i = blockIdx.x * blockDim.x + threadIdx.x;
    if (i >= n) return;
    float a00 = Lp[0 * (size_t)n + i];
    float a01 = Lp[1 * (size_t)n + i];
    float a02 = Lp[2 * (size_t)n + i];
    float a11 = Lp[3 * (size_t)n + i];
    float a12 = Lp[4 * (size_t)n + i];
    float a22 = Lp[5 * (size_t)n + i];
    float A[3][3] = {{a00, a01, a02}, {a01, a11, a12}, {a02, a12, a22}};
    float V[3][3];
    eigh3(A, V);
    float e0 = expf(A[0][0]);
    float e1 = expf(A[1][1]);
    float e2 = expf(A[2][2]);
    float m00 = V[0][0]*e0*V[0][0] + V[0][1]*e1*V[0][1] + V[0][2]*e2*V[0][2];
    float m01 = V[0][0]*e0*V[1][0] + V[0][1]*e1*V[1][1] + V[0][2]*e2*V[1][2];
    float m02 = V[0][0]*e0*V[2][0] + V[0][1]*e1*V[2][1] + V[0][2]*e2*V[2][2];
    float m11 = V[1][0]*e0*V[1][0] + V[1][1]*e1*V[1][1] + V[1][2]*e2*V[1][2];
    float m12 = V[1][0]*e0*V[2][0] + V[1][1]*e1*V[2][1] + V[1][2]*e2*V[2][2];
    float m22 = V[2][0]*e0*V[2][0] + V[2][1]*e1*V[2][1] + V[2][2]*e2*V[2][2];
    float* o = out + (size_t)i * 9;
    o[0] = m00; o[1] = m01; o[2] = m02;
    o[3] = m01; o[4] = m11; o[5] = m12;
    o[6] = m02; o[7] = m12; o[8] = m22;
}

// ---------------------------------------------------------------------------
// Conv v7. Planar [48][C][H][W] log field, fused virtual pre-pad.
// Block = 256 threads (4 waves). Wave w: co-group (w % NG), y-subtile (w / NG).
// Lane: row = l>>3 (8 rows), xq = (l&7)*4 (32 cols, 4 px/thread).
// Weights in LDS co-major; per cc: batch-load K^2 weight float4s + K pixel
// rows (2x float4 each) into regs, then a pure FMA block.
// ---------------------------------------------------------------------------
template<int CI, int CO, int K>
__global__ __launch_bounds__(256, 4)
void conv_tile(const float* __restrict__ in, float* __restrict__ out,
               const float* __restrict__ wn, int Hin, int Win, int pad) {
    constexpr int COT = (CO < 4) ? CO : 4;
    constexpr int NG = CO / COT;        // co groups (1,2,4)
    constexpr int YS = 4 / NG;          // y subtiles per block
    constexpr int BH = 8 * YS;          // block tile height
    constexpr int BW = 32;              // block tile width
    constexpr int CC = (CI > 8) ? 8 : CI;
    constexpr int THI = BH + K - 1;
    constexpr int TWI = BW + K - 1;
    constexpr int ROWW = (TWI + 3) & ~3;
    constexpr int NW = CI * K * K * CO;

    __shared__ float wl[NW];
    __shared__ float itile[CC][THI][ROWW];

    const int tid = threadIdx.x;
    const int wv = __builtin_amdgcn_readfirstlane(tid >> 6);
    const int cog = wv % NG;            // wave-uniform co group
    const int ys = wv / NG;             // wave-uniform y subtile
    const int l = tid & 63;
    const int row = l >> 3;             // 0..7
    const int xq = (l & 7) * 4;         // 0,4,...,28

    const int nb = blockIdx.z;
    const int gy0 = blockIdx.y * BH;
    const int gx0 = blockIdx.x * BW;
    const int Ho = Hin + pad - K + 1;
    const int Wo = Win + pad - K + 1;

    // stage softmaxed weights once: wl[idx*CO + co], idx=(ci*K+kh)*K+kw
    for (int i = tid; i < NW; i += 256) {
        int co = i % CO;
        int idx = i / CO;
        int kw = idx % K; int t = idx / K;
        int kh = t % K; int ci = t / K;
        wl[i] = wn[((co * CI + ci) * K + kh) * K + kw];
    }

    float acc[COT][4];
#pragma unroll
    for (int c2 = 0; c2 < COT; ++c2)
#pragma unroll
        for (int p = 0; p < 4; ++p) acc[c2][p] = 0.f;

    const int srow = ys * 8 + row;      // row within block tile

    for (int c0 = 0; c0 < CI; c0 += CC) {
        __syncthreads();
#pragma unroll 1
        for (int cc = 0; cc < CC; ++cc) {
            const float* ibase = in + ((size_t)(nb * CI + c0 + cc) * Hin) * Win;
            for (int idx = tid; idx < THI * TWI; idx += 256) {
                int r = idx / TWI;
                int c = idx - r * TWI;
                int gy = gy0 + r, gx = gx0 + c;
                float v = 0.f;
                if (gy >= pad && gy < Hin && gx >= pad && gx < Win)
                    v = ibase[(size_t)(gy - pad) * Win + (gx - pad)];
                itile[cc][r][c] = v;
            }
        }
        __syncthreads();
#pragma unroll 1
        for (int cc = 0; cc < CC; ++cc) {
            const int ci = c0 + cc;
            // batch-load weights for this (ci, co-group) into registers
            float wreg[K * K][COT];
            if constexpr (COT == 4) {
#pragma unroll
                for (int kk = 0; kk < K * K; ++kk) {
                    float4 wq = *(const float4*)&wl[(ci * K * K + kk) * CO + cog * COT];
                    wreg[kk][0] = wq.x; wreg[kk][1] = wq.y;
                    wreg[kk][2] = wq.z; wreg[kk][3] = wq.w;
                }
            } else {
#pragma unroll
                for (int kk = 0; kk < K * K; ++kk)
                    wreg[kk][0] = wl[(ci * K * K + kk) * CO];
            }
            // batch-load K pixel rows (8 floats each) into registers
            float px[K][8];
#pragma unroll
            for (int kh = 0; kh < K; ++kh) {
                const float* rp = &itile[cc][srow + kh][xq];
                float4 a = *(const float4*)rp;
                float4 b = *(const float4*)(rp + 4);
                px[kh][0] = a.x; px[kh][1] = a.y; px[kh][2] = a.z; px[kh][3] = a.w;
                px[kh][4] = b.x; px[kh][5] = b.y; px[kh][6] = b.z; px[kh][7] = b.w;
            }
            // pure FMA block
#pragma unroll
            for (int kh = 0; kh < K; ++kh)
#pragma unroll
                for (int kw = 0; kw < K; ++kw)
#pragma unroll
                    for (int c2 = 0; c2 < COT; ++c2)
#pragma unroll
                        for (int p = 0; p < 4; ++p)
                            acc[c2][p] = fmaf(px[kh][p + kw], wreg[kh * K + kw][c2],
                                              acc[c2][p]);
        }
    }

    const int oy = gy0 + srow;
    const int ox0 = gx0 + xq;
    if (oy < Ho) {
#pragma unroll
        for (int c2 = 0; c2 < COT; ++c2) {
            float* ob = out + ((size_t)(nb * CO + cog * COT + c2) * Ho + oy) * Wo + ox0;
#pragma unroll
            for (int p = 0; p < 4; ++p)
                if (ox0 + p < Wo) ob[p] = acc[c2][p];
        }
    }
}

extern "C" void kernel_launch(void* const* d_in, const int* in_sizes, int n_in,
                              void* d_out, int out_size, void* d_ws, size_t ws_size,
                              hipStream_t stream) {
    const float* x = (const float*)d_in[0];
    float* out = (float*)d_out;
    float* ws = (float*)d_ws;

    static const int CiA[10]  = {1, 4, 8, 16, 16, 8, 16, 16, 8, 4};
    static const int CoA[10]  = {4, 8, 16, 16, 8, 16, 16, 8, 4, 1};
    static const int KA[10]   = {3, 3, 3, 2, 2, 2, 2, 3, 3, 3};
    static const int PREPAD[10] = {0, 0, 0, 0, 0, 2, 2, 4, 4, 4};

    int wnoff[11]; wnoff[0] = 0;
    for (int l = 0; l < 10; ++l)
        wnoff[l + 1] = wnoff[l] + CoA[l] * CiA[l] * KA[l] * KA[l];

    float* wn = ws;                       // softmaxed weights (< 8192 floats)
    const size_t BUF = 6900000;
    float* bufA = ws + 8192;
    float* bufB = bufA + BUF;

    WP wp;
    for (int l = 0; l < 10; ++l) {
        wp.src[l] = (const float*)d_in[1 + l];
        wp.dst[l] = wn + wnoff[l];
        wp.Co[l] = CoA[l];
        wp.n[l] = CiA[l] * KA[l] * KA[l];
    }

    const int NB = 48;                    // 6 comps * 8 batch
    const int NMAT = 8 * 96 * 96;
    // fused: blocks 0..9 softmax, blocks 10.. logm
    prep_k<<<10 + (NMAT + 255) / 256, 256, 0, stream>>>(wp, x, bufA, NMAT);

    float* cur = bufA;
    float* nxt = bufB;
    int H = 96, W = 96;                   // stored dims of cur

#define RUN_LAYER(L, CI_, CO_, K_)                                          \
    {                                                                       \
        int pad = PREPAD[L];                                                \
        int Ho = H + pad - K_ + 1, Wo = W + pad - K_ + 1;                   \
        constexpr int COT_ = (CO_ < 4) ? CO_ : 4;                           \
        constexpr int NG_ = CO_ / COT_;                                     \
        constexpr int BH_ = 8 * (4 / NG_);                                  \
        dim3 grd((Wo + 31) / 32, (Ho + BH_ - 1) / BH_, NB);                 \
        conv_tile<CI_, CO_, K_><<<grd, 256, 0, stream>>>(                   \
            cur, nxt, wn + wnoff[L], H, W, pad);                            \
        { float* t = cur; cur = nxt; nxt = t; }                             \
        H = Ho; W = Wo;                                                     \
    }

    RUN_LAYER(0, 1, 4, 3)
    RUN_LAYER(1, 4, 8, 3)
    RUN_LAYER(2, 8, 16, 3)
    RUN_LAYER(3, 16, 16, 2)
    RUN_LAYER(4, 16, 8, 2)
    RUN_LAYER(5, 8, 16, 2)
    RUN_LAYER(6, 16, 16, 2)
    RUN_LAYER(7, 16, 8, 3)
    RUN_LAYER(8, 8, 4, 3)
    RUN_LAYER(9, 4, 1, 3)
#undef RUN_LAYER

    expm_k<<<(NMAT + 255) / 256, 256, 0, stream>>>(cur, out, NMAT);
}

// Round 9
// 239.626 us; speedup vs baseline: 1.1722x; 1.1722x over previous
//
#include <hip/hip_runtime.h>
#include <math.h>

// ---------------------------------------------------------------------------
// ManifoldNet SPD network, fused in log-domain.
// v9: pre-padded buffer layout (pads baked into producer writes + strip-zero
// kernels) -> staging has zero bounds checks and uses global_load_lds(16B)
// direct-to-LDS. Compute phase clustered via sched_group_barrier
// (DS_READ block then FMA block per channel).
// ---------------------------------------------------------------------------

#define DEVFN __device__ __forceinline__

#define GLD16(g, l)                                                         \
    __builtin_amdgcn_global_load_lds(                                       \
        (const __attribute__((address_space(1))) void*)(g),                 \
        (__attribute__((address_space(3))) void*)(l), 16, 0, 0)

DEVFN void jrot(float A[3][3], float V[3][3], int p, int q) {
    float apq = A[p][q];
    if (fabsf(apq) < 1e-30f) return;
    float app = A[p][p], aqq = A[q][q];
    float tau = (aqq - app) / (2.0f * apq);
    float t = copysignf(1.0f, tau) / (fabsf(tau) + sqrtf(1.0f + tau * tau));
    float c = rsqrtf(1.0f + t * t);
    float s = t * c;
    int r = 3 - p - q;
    float arp = A[r][p], arq = A[r][q];
    A[p][p] = app - t * apq;
    A[q][q] = aqq + t * apq;
    A[p][q] = 0.0f; A[q][p] = 0.0f;
    A[r][p] = c * arp - s * arq; A[p][r] = A[r][p];
    A[r][q] = s * arp + c * arq; A[q][r] = A[r][q];
#pragma unroll
    for (int i = 0; i < 3; ++i) {
        float vip = V[i][p], viq = V[i][q];
        V[i][p] = c * vip - s * viq;
        V[i][q] = s * vip + c * viq;
    }
}

DEVFN void eigh3(float A[3][3], float V[3][3]) {
    V[0][0] = 1.f; V[0][1] = 0.f; V[0][2] = 0.f;
    V[1][0] = 0.f; V[1][1] = 1.f; V[1][2] = 0.f;
    V[2][0] = 0.f; V[2][1] = 0.f; V[2][2] = 1.f;
#pragma unroll
    for (int s = 0; s < 6; ++s) {
        jrot(A, V, 0, 1);
        jrot(A, V, 0, 2);
        jrot(A, V, 1, 2);
    }
}

struct WP {
    const float* src[10];
    float* dst[10];
    int Co[10];
    int n[10];
};

// blocks 0..9: wave-parallel softmax; blocks 10..: logm -> planar [6][n].
__global__ __launch_bounds__(256)
void prep_k(WP wp, const float* __restrict__ x, float* __restrict__ out, int n) {
    if (blockIdx.x < 10) {
        const int l = blockIdx.x;
        const int wv = threadIdx.x >> 6;
        const int lane = threadIdx.x & 63;
        const int Co = wp.Co[l], nn = wp.n[l];
        for (int co = wv; co < Co; co += 4) {
            const float* src = wp.src[l] + (size_t)co * nn;
            float v0 = (lane < nn) ? src[lane] : -1e30f;
            float v1 = (lane + 64 < nn) ? src[lane + 64] : -1e30f;
            float v2 = (lane + 128 < nn) ? src[lane + 128] : -1e30f;
            float mx = fmaxf(fmaxf(v0, v1), v2);
#pragma unroll
            for (int off = 32; off; off >>= 1)
                mx = fmaxf(mx, __shfl_xor(mx, off));
            float e0 = (lane < nn) ? expf(v0 - mx) : 0.f;
            float e1 = (lane + 64 < nn) ? expf(v1 - mx) : 0.f;
            float e2 = (lane + 128 < nn) ? expf(v2 - mx) : 0.f;
            float s = e0 + e1 + e2;
#pragma unroll
            for (int off = 32; off; off >>= 1)
                s += __shfl_xor(s, off);
            float inv = 1.0f / s;
            float* dst = wp.dst[l] + (size_t)co * nn;
            if (lane < nn) dst[lane] = e0 * inv;
            if (lane + 64 < nn) dst[lane + 64] = e1 * inv;
            if (lane + 128 < nn) dst[lane + 128] = e2 * inv;
        }
        return;
    }
    int i = (blockIdx.x - 10) * 256 + threadIdx.x;
    if (i >= n) return;
    const float* m = x + (size_t)i * 9;
    float a01 = 0.5f * (m[1] + m[3]);
    float a02 = 0.5f * (m[2] + m[6]);
    float a12 = 0.5f * (m[5] + m[7]);
    float A[3][3] = {{m[0], a01, a02}, {a01, m[4], a12}, {a02, a12, m[8]}};
    float V[3][3];
    eigh3(A, V);
    float d0 = logf(fmaxf(A[0][0], 1e-30f));
    float d1 = logf(fmaxf(A[1][1], 1e-30f));
    float d2 = logf(fmaxf(A[2][2], 1e-30f));
    float L00 = V[0][0]*d0*V[0][0] + V[0][1]*d1*V[0][1] + V[0][2]*d2*V[0][2];
    float L01 = V[0][0]*d0*V[1][0] + V[0][1]*d1*V[1][1] + V[0][2]*d2*V[1][2];
    float L02 = V[0][0]*d0*V[2][0] + V[0][1]*d1*V[2][1] + V[0][2]*d2*V[2][2];
    float L11 = V[1][0]*d0*V[1][0] + V[1][1]*d1*V[1][1] + V[1][2]*d2*V[1][2];
    float L12 = V[1][0]*d0*V[2][0] + V[1][1]*d1*V[2][1] + V[1][2]*d2*V[2][2];
    float L22 = V[2][0]*d0*V[2][0] + V[2][1]*d1*V[2][1] + V[2][2]*d2*V[2][2];
    out[0 * (size_t)n + i] = L00;
    out[1 * (size_t)n + i] = L01;
    out[2 * (size_t)n + i] = L02;
    out[3 * (size_t)n + i] = L11;
    out[4 * (size_t)n + i] = L12;
    out[5 * (size_t)n + i] = L22;
}

__global__ void expm_k(const float* __restrict__ Lp, float* __restrict__ out, int n) {
    int i = blockIdx.x * blockDim.x + threadIdx.x;
    if (i >= n) return;
    float a00 = Lp[0 * (size_t)n + i];
    float a01 = Lp[1 * (size_t)n + i];
    float a02 = Lp[2 * (size_t)n + i];
    float a11 = Lp[3 * (size_t)n + i];
    float a12 = Lp[4 * (size_t)n + i];
    float a22 = Lp[5 * (size_t)n + i];
    float A[3][3] = {{a00, a01, a02}, {a01, a11, a12}, {a02, a12, a22}};
    float V[3][3];
    eigh3(A, V);
    float e0 = expf(A[0][0]);
    float e1 = expf(A[1][1]);
    float e2 = expf(A[2][2]);
    float m00 = V[0][0]*e0*V[0][0] + V[0][1]*e1*V[0][1] + V[0][2]*e2*V[0][2];
    float m01 = V[0][0]*e0*V[1][0] + V[0][1]*e1*V[1][1] + V[0][2]*e2*V[1][2];
    float m02 = V[0][0]*e0*V[2][0] + V[0][1]*e1*V[2][1] + V[0][2]*e2*V[2][2];
    float m11 = V[1][0]*e0*V[1][0] + V[1][1]*e1*V[1][1] + V[1][2]*e2*V[1][2];
    float m12 = V[1][0]*e0*V[2][0] + V[1][1]*e1*V[2][1] + V[1][2]*e2*V[2][2];
    float m22 = V[2][0]*e0*V[2][0] + V[2][1]*e1*V[2][1] + V[2][2]*e2*V[2][2];
    float* o = out + (size_t)i * 9;
    o[0] = m00; o[1] = m01; o[2] = m02;
    o[3] = m01; o[4] = m11; o[5] = m12;
    o[6] = m02; o[7] = m12; o[8] = m22;
}

// Zero the pad border strips of a pre-padded buffer [48][C][Hv][W4]:
// rows [0,p) and [Hv-p,Hv) full width; mid rows: cols [0,p) and [Wv-p,W4).
__global__ void strips_k(float* buf, int C, int Hv, int W4, int Wv, int p) {
    int band = p * W4;
    int rw = W4 - Wv + p;             // right strip width (incl align junk)
    int midw = p + rw;
    int S = 2 * band + (Hv - 2 * p) * midw;
    size_t total = (size_t)48 * C * S;
    size_t i = (size_t)blockIdx.x * 256 + threadIdx.x;
    if (i >= total) return;
    int plane = (int)(i / S);
    int s = (int)(i - (size_t)plane * S);
    int r, c;
    if (s < band) { r = s / W4; c = s - r * W4; }
    else if (s < 2 * band) { int t = s - band; r = Hv - p + t / W4; c = t % W4; }
    else {
        int t = s - 2 * band;
        r = p + t / midw;
        int cc = t - (t / midw) * midw;
        c = (cc < p) ? cc : (Wv - p + (cc - p));
    }
    buf[(size_t)plane * Hv * W4 + (size_t)r * W4 + c] = 0.f;
}

// ---------------------------------------------------------------------------
// Conv v9. Input: pre-padded planar [48][CI][Hv][W4in] (no bounds checks!).
// Output: pre-padded planar [48][CO][HvOut][W4out] with crop+shift by p2.
// Block 256 (4 waves). Wave: cog = wv%NG, ys = wv/NG. Lane: row l>>3, 4 px.
// Staging: global_load_lds 16B direct. Compute: SGB-clustered DS_READ+FMA.
// ---------------------------------------------------------------------------
template<int CI, int CO, int K>
__global__ __launch_bounds__(256, 4)
void conv_tile(const float* __restrict__ in, float* __restrict__ out,
               const float* __restrict__ wn,
               int Hv, int W4in, int Ho, int Wo, int p2, int HvOut, int W4out) {
    constexpr int COT = (CO < 4) ? CO : 4;
    constexpr int NG = CO / COT;
    constexpr int YS = 4 / NG;
    constexpr int BH = 8 * YS;
    constexpr int K2 = K * K;
    constexpr int THI = BH + K - 1;
    constexpr int TWI = 32 + K - 1;
    constexpr int ROWW = (TWI + 3) & ~3;
    constexpr int CHS = THI * ROWW;       // floats per channel tile
    constexpr int TILE = CI * CHS;
    constexpr int NW = CI * K2 * CO;

    __shared__ __align__(16) float wl[NW];
    __shared__ __align__(16) float tile[TILE];

    const int tid = threadIdx.x;
    const int wv = __builtin_amdgcn_readfirstlane(tid >> 6);
    const int cog = wv % NG;
    const int ys = wv / NG;
    const int l = tid & 63;
    const int srow = ys * 8 + (l >> 3);
    const int xq = (l & 7) * 4;

    const int nb = blockIdx.z;
    const int gy0 = blockIdx.y * BH;
    const int gx0 = blockIdx.x * 32;

    // ---- stage input tile via global_load_lds (no bounds checks) ----
    const size_t planeIn = (size_t)Hv * W4in;
    const float* inb = in + (size_t)nb * CI * planeIn + (size_t)gy0 * W4in + gx0;
    for (int o = tid * 4; o < TILE; o += 1024) {
        int ch = o / CHS;
        int rem = o - ch * CHS;
        int r = rem / ROWW;
        int c = rem - r * ROWW;
        const float* g = inb + ch * planeIn + (size_t)r * W4in + c;
        GLD16(g, &tile[o]);
    }
    // ---- stage softmaxed weights: wl[(ci*K2 + kh*K+kw)*CO + co] ----
    for (int i = tid; i < NW; i += 256) {
        int co = i % CO;
        int idx = i / CO;
        int kw = idx % K; int t = idx / K;
        int kh = t % K; int ci = t / K;
        wl[i] = wn[((co * CI + ci) * K + kh) * K + kw];
    }
    __syncthreads();   // drains vmcnt (gload_lds) + lgkmcnt (ds_write)

    float acc[COT][4];
#pragma unroll
    for (int c2 = 0; c2 < COT; ++c2)
#pragma unroll
        for (int p = 0; p < 4; ++p) acc[c2][p] = 0.f;

#pragma unroll 1
    for (int cc = 0; cc < CI; ++cc) {
        const float* tb = tile + cc * CHS + srow * ROWW + xq;
        float rv[K][4 + K - 1];
#pragma unroll
        for (int kh = 0; kh < K; ++kh) {
            float4 a = *(const float4*)(tb + kh * ROWW);
            float4 b = *(const float4*)(tb + kh * ROWW + 4);
            rv[kh][0] = a.x; rv[kh][1] = a.y; rv[kh][2] = a.z; rv[kh][3] = a.w;
            rv[kh][4] = b.x;
            if constexpr (K == 3) rv[kh][5] = b.y;
        }
        const float* wb = wl + cc * K2 * CO + cog * COT;
#pragma unroll
        for (int kh = 0; kh < K; ++kh) {
#pragma unroll
            for (int kw = 0; kw < K; ++kw) {
                if constexpr (COT == 4) {
                    float4 wq = *(const float4*)(wb + (kh * K + kw) * CO);
                    float wqa[4] = {wq.x, wq.y, wq.z, wq.w};
#pragma unroll
                    for (int c2 = 0; c2 < 4; ++c2)
#pragma unroll
                        for (int p = 0; p < 4; ++p)
                            acc[c2][p] = fmaf(rv[kh][p + kw], wqa[c2], acc[c2][p]);
                } else {
                    float w0 = wb[(kh * K + kw) * CO];
#pragma unroll
                    for (int p = 0; p < 4; ++p)
                        acc[0][p] = fmaf(rv[kh][p + kw], w0, acc[0][p]);
                }
            }
        }
        // cluster: all DS reads of this cc first, then the FMA block
        __builtin_amdgcn_sched_group_barrier(0x100, 2 * K + K2, 0); // DS_READ
        __builtin_amdgcn_sched_group_barrier(0x002, K2 * COT * 4 + 8, 0); // VALU
    }

    // ---- epilogue: crop by p2 and write shifted into pre-padded output ----
    const int oy = gy0 + srow;
    const int x0 = gx0 + xq;
    if (oy < Ho - p2) {
        const size_t planeOut = (size_t)HvOut * W4out;
#pragma unroll
        for (int c2 = 0; c2 < COT; ++c2) {
            float* ob = out + ((size_t)nb * CO + cog * COT + c2) * planeOut
                        + (size_t)(oy + p2) * W4out + p2 + x0;
#pragma unroll
            for (int p = 0; p < 4; ++p)
                if (x0 + p < Wo - p2) ob[p] = acc[c2][p];
        }
    }
}

extern "C" void kernel_launch(void* const* d_in, const int* in_sizes, int n_in,
                              void* d_out, int out_size, void* d_ws, size_t ws_size,
                              hipStream_t stream) {
    const float* x = (const float*)d_in[0];
    float* out = (float*)d_out;
    float* ws = (float*)d_ws;

    static const int CiA[10] = {1, 4, 8, 16, 16, 8, 16, 16, 8, 4};
    static const int CoA[10] = {4, 8, 16, 16, 8, 16, 16, 8, 4, 1};
    static const int KA[10]  = {3, 3, 3, 2, 2, 2, 2, 3, 3, 3};

    int wnoff[11]; wnoff[0] = 0;
    for (int l = 0; l < 10; ++l)
        wnoff[l + 1] = wnoff[l] + CoA[l] * CiA[l] * KA[l] * KA[l];

    float* wn = ws;
    float* bufA = ws + 8192;          // inputs of L0,L2,L4,L6,L8 (max 6.43M)
    float* bufB = bufA + 6450000;     // inputs of L1,L3,L5,L7,L9 (max 6.94M)

    WP wp;
    for (int l = 0; l < 10; ++l) {
        wp.src[l] = (const float*)d_in[1 + l];
        wp.dst[l] = wn + wnoff[l];
        wp.Co[l] = CoA[l];
        wp.n[l] = CiA[l] * KA[l] * KA[l];
    }

    const int NMAT = 8 * 96 * 96;
    prep_k<<<10 + (NMAT + 255) / 256, 256, 0, stream>>>(wp, x, bufA, NMAT);

    float* cur = bufA;
    float* nxt = bufB;

    // Per-layer geometry (virtual = pre-padded):
    //            L:    0   1   2   3   4   5   6   7   8   9
    // Hv_in:         96  94  92  90  89  90  91  94  96  98
    // W4in:          96  96  92  92  92  92  92  96  96 100
    // Ho=Wo:         94  92  90  89  88  89  90  92  94  96
    // p2(next pad):   0   0   0   0   2   2   4   4   4   0
    // HvOut:         94  92  90  89  90  91  94  96  98  96
    // W4out:         96  92  92  92  92  92  96  96 100  96

#define RUN_LAYER(CI_, CO_, K_, HV_, W4IN_, HO_, P2_, HVOUT_, W4OUT_, L_)   \
    {                                                                       \
        constexpr int COT_ = (CO_ < 4) ? CO_ : 4;                           \
        constexpr int NG_ = CO_ / COT_;                                     \
        constexpr int BH_ = 8 * (4 / NG_);                                  \
        dim3 grd((HO_ + 31) / 32, (HO_ + BH_ - 1) / BH_, 48);               \
        conv_tile<CI_, CO_, K_><<<grd, 256, 0, stream>>>(                   \
            cur, nxt, wn + wnoff[L_], HV_, W4IN_, HO_, HO_, P2_, HVOUT_,    \
            W4OUT_);                                                        \
        { float* t = cur; cur = nxt; nxt = t; }                             \
        if (P2_ > 0) {                                                      \
            int band = P2_ * W4OUT_;                                        \
            int midw = P2_ + (W4OUT_ - (HO_ + P2_) + P2_);                  \
            size_t total = (size_t)48 * CO_ *                               \
                (2 * band + (HVOUT_ - 2 * P2_) * midw);                     \
            strips_k<<<(unsigned)((total + 255) / 256), 256, 0, stream>>>(  \
                cur, CO_, HVOUT_, W4OUT_, HO_ + P2_, P2_);                  \
        }                                                                   \
    }

    RUN_LAYER(1,  4, 3, 96, 96, 94, 0, 94, 96, 0)
    RUN_LAYER(4,  8, 3, 94, 96, 92, 0, 92, 92, 1)
    RUN_LAYER(8, 16, 3, 92, 92, 90, 0, 90, 92, 2)
    RUN_LAYER(16, 16, 2, 90, 92, 89, 0, 89, 92, 3)
    RUN_LAYER(16, 8, 2, 89, 92, 88, 2, 90, 92, 4)
    RUN_LAYER(8, 16, 2, 90, 92, 89, 2, 91, 92, 5)
    RUN_LAYER(16, 16, 2, 91, 92, 90, 4, 94, 96, 6)
    RUN_LAYER(16, 8, 3, 94, 96, 92, 4, 96, 96, 7)
    RUN_LAYER(8,  4, 3, 96, 96, 94, 4, 98, 100, 8)
    RUN_LAYER(4,  1, 3, 98, 100, 96, 0, 96, 96, 9)
#undef RUN_LAYER

    expm_k<<<(NMAT + 255) / 256, 256, 0, stream>>>(cur, out, NMAT);
}

// Round 10
// 229.043 us; speedup vs baseline: 1.2263x; 1.0462x over previous
//
#include <hip/hip_runtime.h>
#include <math.h>

// ---------------------------------------------------------------------------
// ManifoldNet SPD network, fused in log-domain.
// v10: conv writes the FULL padded output frame (interior = conv value,
// border = 0) -> the 5 strip-zero kernels are gone; 12 dispatches total.
// Staging via global_load_lds(16B) with a fixed 4-float lead pad for
// alignment; p2=2 layers use an 8B-aligned float2 pixel-read path.
// ---------------------------------------------------------------------------

#define DEVFN __device__ __forceinline__

#define GLD16(g, l)                                                         \
    __builtin_amdgcn_global_load_lds(                                       \
        (const __attribute__((address_space(1))) void*)(g),                 \
        (__attribute__((address_space(3))) void*)(l), 16, 0, 0)

DEVFN void jrot(float A[3][3], float V[3][3], int p, int q) {
    float apq = A[p][q];
    if (fabsf(apq) < 1e-30f) return;
    float app = A[p][p], aqq = A[q][q];
    float tau = (aqq - app) / (2.0f * apq);
    float t = copysignf(1.0f, tau) / (fabsf(tau) + sqrtf(1.0f + tau * tau));
    float c = rsqrtf(1.0f + t * t);
    float s = t * c;
    int r = 3 - p - q;
    float arp = A[r][p], arq = A[r][q];
    A[p][p] = app - t * apq;
    A[q][q] = aqq + t * apq;
    A[p][q] = 0.0f; A[q][p] = 0.0f;
    A[r][p] = c * arp - s * arq; A[p][r] = A[r][p];
    A[r][q] = s * arp + c * arq; A[q][r] = A[r][q];
#pragma unroll
    for (int i = 0; i < 3; ++i) {
        float vip = V[i][p], viq = V[i][q];
        V[i][p] = c * vip - s * viq;
        V[i][q] = s * vip + c * viq;
    }
}

DEVFN void eigh3(float A[3][3], float V[3][3]) {
    V[0][0] = 1.f; V[0][1] = 0.f; V[0][2] = 0.f;
    V[1][0] = 0.f; V[1][1] = 1.f; V[1][2] = 0.f;
    V[2][0] = 0.f; V[2][1] = 0.f; V[2][2] = 1.f;
#pragma unroll
    for (int s = 0; s < 6; ++s) {
        jrot(A, V, 0, 1);
        jrot(A, V, 0, 2);
        jrot(A, V, 1, 2);
    }
}

struct WP {
    const float* src[10];
    float* dst[10];
    int Co[10];
    int n[10];
};

// blocks 0..9: wave-parallel softmax; blocks 10..: logm -> planar [6][n].
__global__ __launch_bounds__(256)
void prep_k(WP wp, const float* __restrict__ x, float* __restrict__ out, int n) {
    if (blockIdx.x < 10) {
        const int l = blockIdx.x;
        const int wv = threadIdx.x >> 6;
        const int lane = threadIdx.x & 63;
        const int Co = wp.Co[l], nn = wp.n[l];
        for (int co = wv; co < Co; co += 4) {
            const float* src = wp.src[l] + (size_t)co * nn;
            float v0 = (lane < nn) ? src[lane] : -1e30f;
            float v1 = (lane + 64 < nn) ? src[lane + 64] : -1e30f;
            float v2 = (lane + 128 < nn) ? src[lane + 128] : -1e30f;
            float mx = fmaxf(fmaxf(v0, v1), v2);
#pragma unroll
            for (int off = 32; off; off >>= 1)
                mx = fmaxf(mx, __shfl_xor(mx, off));
            float e0 = (lane < nn) ? expf(v0 - mx) : 0.f;
            float e1 = (lane + 64 < nn) ? expf(v1 - mx) : 0.f;
            float e2 = (lane + 128 < nn) ? expf(v2 - mx) : 0.f;
            float s = e0 + e1 + e2;
#pragma unroll
            for (int off = 32; off; off >>= 1)
                s += __shfl_xor(s, off);
            float inv = 1.0f / s;
            float* dst = wp.dst[l] + (size_t)co * nn;
            if (lane < nn) dst[lane] = e0 * inv;
            if (lane + 64 < nn) dst[lane + 64] = e1 * inv;
            if (lane + 128 < nn) dst[lane + 128] = e2 * inv;
        }
        return;
    }
    int i = (blockIdx.x - 10) * 256 + threadIdx.x;
    if (i >= n) return;
    const float* m = x + (size_t)i * 9;
    float a01 = 0.5f * (m[1] + m[3]);
    float a02 = 0.5f * (m[2] + m[6]);
    float a12 = 0.5f * (m[5] + m[7]);
    float A[3][3] = {{m[0], a01, a02}, {a01, m[4], a12}, {a02, a12, m[8]}};
    float V[3][3];
    eigh3(A, V);
    float d0 = logf(fmaxf(A[0][0], 1e-30f));
    float d1 = logf(fmaxf(A[1][1], 1e-30f));
    float d2 = logf(fmaxf(A[2][2], 1e-30f));
    float L00 = V[0][0]*d0*V[0][0] + V[0][1]*d1*V[0][1] + V[0][2]*d2*V[0][2];
    float L01 = V[0][0]*d0*V[1][0] + V[0][1]*d1*V[1][1] + V[0][2]*d2*V[1][2];
    float L02 = V[0][0]*d0*V[2][0] + V[0][1]*d1*V[2][1] + V[0][2]*d2*V[2][2];
    float L11 = V[1][0]*d0*V[1][0] + V[1][1]*d1*V[1][1] + V[1][2]*d2*V[1][2];
    float L12 = V[1][0]*d0*V[2][0] + V[1][1]*d1*V[2][1] + V[1][2]*d2*V[2][2];
    float L22 = V[2][0]*d0*V[2][0] + V[2][1]*d1*V[2][1] + V[2][2]*d2*V[2][2];
    out[0 * (size_t)n + i] = L00;
    out[1 * (size_t)n + i] = L01;
    out[2 * (size_t)n + i] = L02;
    out[3 * (size_t)n + i] = L11;
    out[4 * (size_t)n + i] = L12;
    out[5 * (size_t)n + i] = L22;
}

__global__ void expm_k(const float* __restrict__ Lp, float* __restrict__ out, int n) {
    int i = blockIdx.x * blockDim.x + threadIdx.x;
    if (i >= n) return;
    float a00 = Lp[0 * (size_t)n + i];
    float a01 = Lp[1 * (size_t)n + i];
    float a02 = Lp[2 * (size_t)n + i];
    float a11 = Lp[3 * (size_t)n + i];
    float a12 = Lp[4 * (size_t)n + i];
    float a22 = Lp[5 * (size_t)n + i];
    float A[3][3] = {{a00, a01, a02}, {a01, a11, a12}, {a02, a12, a22}};
    float V[3][3];
    eigh3(A, V);
    float e0 = expf(A[0][0]);
    float e1 = expf(A[1][1]);
    float e2 = expf(A[2][2]);
    float m00 = V[0][0]*e0*V[0][0] + V[0][1]*e1*V[0][1] + V[0][2]*e2*V[0][2];
    float m01 = V[0][0]*e0*V[1][0] + V[0][1]*e1*V[1][1] + V[0][2]*e2*V[1][2];
    float m02 = V[0][0]*e0*V[2][0] + V[0][1]*e1*V[2][1] + V[0][2]*e2*V[2][2];
    float m11 = V[1][0]*e0*V[1][0] + V[1][1]*e1*V[1][1] + V[1][2]*e2*V[1][2];
    float m12 = V[1][0]*e0*V[2][0] + V[1][1]*e1*V[2][1] + V[1][2]*e2*V[2][2];
    float m22 = V[2][0]*e0*V[2][0] + V[2][1]*e1*V[2][1] + V[2][2]*e2*V[2][2];
    float* o = out + (size_t)i * 9;
    o[0] = m00; o[1] = m01; o[2] = m02;
    o[3] = m01; o[4] = m11; o[5] = m12;
    o[6] = m02; o[7] = m12; o[8] = m22;
}

// ---------------------------------------------------------------------------
// Conv v10. Input: pre-padded planar [48][CI][Hv][W4in]. Output: FULL padded
// frame [48][CO][HvOut][W4out]; interior rows/cols [P2,Ho) get conv values,
// everything else written 0. Grid covers the whole padded frame.
// Staging: rows [gy0-P2, +THI), cols [gx0-4, +ROWW) via global_load_lds 16B
// (lead pad 4 keeps 16B alignment; OOB reads land in ws slack, masked at
// write). P2==2: pixel reads via float2 (LDS base only 8B-aligned).
// ---------------------------------------------------------------------------
template<int CI, int CO, int K, int P2>
__global__ __launch_bounds__(256, 4)
void conv_tile(const float* __restrict__ in, float* __restrict__ out,
               const float* __restrict__ wn,
               int Hv, int W4in, int Ho, int HvOut, int W4out) {
    constexpr int COT = (CO < 4) ? CO : 4;
    constexpr int NG = CO / COT;
    constexpr int YS = 4 / NG;
    constexpr int BH = 8 * YS;
    constexpr int K2 = K * K;
    constexpr int THI = BH + K - 1;
    constexpr int ROWW = 40;
    constexpr int CHS = THI * ROWW;
    constexpr int TILE = CI * CHS;
    constexpr int NW = CI * K2 * CO;

    __shared__ __align__(16) float wl[NW];
    __shared__ __align__(16) float tile[TILE];

    const int tid = threadIdx.x;
    const int wv = __builtin_amdgcn_readfirstlane(tid >> 6);
    const int cog = wv % NG;
    const int ys = wv / NG;
    const int l = tid & 63;
    const int srow = ys * 8 + (l >> 3);
    const int xq = (l & 7) * 4;

    const int nb = blockIdx.z;
    const int gy0 = blockIdx.y * BH;
    const int gx0 = blockIdx.x * 32;

    // ---- stage input tile: rows gy0-P2.., cols gx0-4.. (16B aligned) ----
    const size_t planeIn = (size_t)Hv * W4in;
    const float* inb = in + (size_t)nb * CI * planeIn
                       + (long)(gy0 - P2) * W4in + (gx0 - 4);
    for (int o = tid * 4; o < TILE; o += 1024) {
        int ch = o / CHS;
        int rem = o - ch * CHS;
        int r = rem / ROWW;
        int c = rem - r * ROWW;
        const float* g = inb + ch * planeIn + (long)r * W4in + c;
        GLD16(g, &tile[o]);
    }
    // ---- stage softmaxed weights: wl[(ci*K2 + kh*K+kw)*CO + co] ----
    for (int i = tid; i < NW; i += 256) {
        int co = i % CO;
        int idx = i / CO;
        int kw = idx % K; int t = idx / K;
        int kh = t % K; int ci = t / K;
        wl[i] = wn[((co * CI + ci) * K + kh) * K + kw];
    }
    __syncthreads();

    float acc[COT][4];
#pragma unroll
    for (int c2 = 0; c2 < COT; ++c2)
#pragma unroll
        for (int p = 0; p < 4; ++p) acc[c2][p] = 0.f;

#pragma unroll 1
    for (int cc = 0; cc < CI; ++cc) {
        const float* tb = tile + cc * CHS + srow * ROWW + (xq + 4 - P2);
        float rv[K][4 + K - 1];
#pragma unroll
        for (int kh = 0; kh < K; ++kh) {
            const float* rp = tb + kh * ROWW;
            if constexpr ((P2 & 3) == 0) {
                float4 a = *(const float4*)rp;
                rv[kh][0] = a.x; rv[kh][1] = a.y; rv[kh][2] = a.z; rv[kh][3] = a.w;
                rv[kh][4] = rp[4];
                if constexpr (K == 3) rv[kh][5] = rp[5];
            } else {
                float2 u0 = *(const float2*)rp;
                float2 u1 = *(const float2*)(rp + 2);
                float2 u2 = *(const float2*)(rp + 4);
                rv[kh][0] = u0.x; rv[kh][1] = u0.y;
                rv[kh][2] = u1.x; rv[kh][3] = u1.y;
                rv[kh][4] = u2.x;
                if constexpr (K == 3) rv[kh][5] = u2.y;
            }
        }
        const float* wb = wl + cc * K2 * CO + cog * COT;
#pragma unroll
        for (int kh = 0; kh < K; ++kh) {
#pragma unroll
            for (int kw = 0; kw < K; ++kw) {
                if constexpr (COT == 4) {
                    float4 wq = *(const float4*)(wb + (kh * K + kw) * CO);
                    float wqa[4] = {wq.x, wq.y, wq.z, wq.w};
#pragma unroll
                    for (int c2 = 0; c2 < 4; ++c2)
#pragma unroll
                        for (int p = 0; p < 4; ++p)
                            acc[c2][p] = fmaf(rv[kh][p + kw], wqa[c2], acc[c2][p]);
                } else {
                    float w0 = wb[(kh * K + kw) * CO];
#pragma unroll
                    for (int p = 0; p < 4; ++p)
                        acc[0][p] = fmaf(rv[kh][p + kw], w0, acc[0][p]);
                }
            }
        }
        __builtin_amdgcn_sched_group_barrier(0x100, ((P2 & 3) ? 3 * K : 2 * K) + K2, 0);
        __builtin_amdgcn_sched_group_barrier(0x002, K2 * COT * 4 + 8, 0);
    }

    // ---- epilogue: write full padded frame (border -> 0) ----
    const int r = gy0 + srow;            // padded-out row
    if (r < HvOut) {
        const bool rin = (r >= P2) && (r < Ho);
        const size_t planeOut = (size_t)HvOut * W4out;
#pragma unroll
        for (int c2 = 0; c2 < COT; ++c2) {
            float* ob = out + ((size_t)nb * CO + cog * COT + c2) * planeOut
                        + (size_t)r * W4out + gx0 + xq;
#pragma unroll
            for (int p = 0; p < 4; ++p) {
                int c = gx0 + xq + p;    // padded-out col
                if (c < W4out) {
                    bool in_ = rin && (c >= P2) && (c < Ho);  // Wo == Ho
                    ob[p] = in_ ? acc[c2][p] : 0.f;
                }
            }
        }
    }
}

extern "C" void kernel_launch(void* const* d_in, const int* in_sizes, int n_in,
                              void* d_out, int out_size, void* d_ws, size_t ws_size,
                              hipStream_t stream) {
    const float* x = (const float*)d_in[0];
    float* out = (float*)d_out;
    float* ws = (float*)d_ws;

    static const int CiA[10] = {1, 4, 8, 16, 16, 8, 16, 16, 8, 4};
    static const int CoA[10] = {4, 8, 16, 16, 8, 16, 16, 8, 4, 1};
    static const int KA[10]  = {3, 3, 3, 2, 2, 2, 2, 3, 3, 3};

    int wnoff[11]; wnoff[0] = 0;
    for (int l = 0; l < 10; ++l)
        wnoff[l + 1] = wnoff[l] + CoA[l] * CiA[l] * KA[l] * KA[l];

    float* wn = ws;
    float* bufA = ws + 8192;          // outputs of L1,L3,L5,L7,L9 (max 6.43M)
    float* bufB = bufA + 6450000;     // outputs of L0,L2,L4,L6,L8 (max 6.93M)

    WP wp;
    for (int l = 0; l < 10; ++l) {
        wp.src[l] = (const float*)d_in[1 + l];
        wp.dst[l] = wn + wnoff[l];
        wp.Co[l] = CoA[l];
        wp.n[l] = CiA[l] * KA[l] * KA[l];
    }

    const int NMAT = 8 * 96 * 96;
    prep_k<<<10 + (NMAT + 255) / 256, 256, 0, stream>>>(wp, x, bufA, NMAT);

    float* cur = bufA;
    float* nxt = bufB;

    // Geometry (verified in v9): per layer L:
    //   input frame (Hv, W4in); conv out Ho=Wo=Hv-K+1; own out-pad P2;
    //   output frame (HvOut=Ho+P2, W4out).
#define RUN_LAYER(L_, CI_, CO_, K_, P2_, HV_, W4IN_, HO_, HVOUT_, W4OUT_)   \
    {                                                                       \
        constexpr int COT_ = (CO_ < 4) ? CO_ : 4;                           \
        constexpr int NG_ = CO_ / COT_;                                     \
        constexpr int BH_ = 8 * (4 / NG_);                                  \
        dim3 grd((W4OUT_ + 31) / 32, (HVOUT_ + BH_ - 1) / BH_, 48);         \
        conv_tile<CI_, CO_, K_, P2_><<<grd, 256, 0, stream>>>(              \
            cur, nxt, wn + wnoff[L_], HV_, W4IN_, HO_, HVOUT_, W4OUT_);     \
        { float* t = cur; cur = nxt; nxt = t; }                             \
    }

    RUN_LAYER(0,  1,  4, 3, 0, 96,  96, 94, 94,  96)
    RUN_LAYER(1,  4,  8, 3, 0, 94,  96, 92, 92,  92)
    RUN_LAYER(2,  8, 16, 3, 0, 92,  92, 90, 90,  92)
    RUN_LAYER(3, 16, 16, 2, 0, 90,  92, 89, 89,  92)
    RUN_LAYER(4, 16,  8, 2, 2, 89,  92, 88, 90,  92)
    RUN_LAYER(5,  8, 16, 2, 2, 90,  92, 89, 91,  92)
    RUN_LAYER(6, 16, 16, 2, 4, 91,  92, 90, 94,  96)
    RUN_LAYER(7, 16,  8, 3, 4, 94,  96, 92, 96,  96)
    RUN_LAYER(8,  8,  4, 3, 4, 96,  96, 94, 98, 100)
    RUN_LAYER(9,  4,  1, 3, 0, 98, 100, 96, 96,  96)
#undef RUN_LAYER

    expm_k<<<(NMAT + 255) / 256, 256, 0, stream>>>(cur, out, NMAT);
}